// Round 4
// baseline (958.311 us; speedup 1.0000x reference)
//
#include <hip/hip_runtime.h>
#include <hip/hip_bf16.h>

// GAT_51788715655952. Atomic-free counting sort of edges by dst (2B src payload);
// per-node wave does online-softmax weighted sum of ys[src]; edge-linear decomposed:
//   agg[i] = deg*(yd[i]+elb) + (sum_e w_e*ys[src_e])/sum_e w_e + wsum[i]*elw[64] + b
// Sort pipeline uses LDS histograms / LDS cursors only (device atomics cost ~30B HBM
// write each on MI355X -- round-3 rocprof: 2.56M atomics = 77MB WRITE, 131us).

#define HID 32
#define NB_SORT 128

typedef unsigned short ushort_t;

// per-block LDS histogram: counts + sum|ea| per dst bin, written as partials.
__global__ void k_part_hist(const int* __restrict__ dst, const float* __restrict__ ea,
                            int* __restrict__ part, float* __restrict__ partw,
                            int E, int nbins, int chunk) {
    extern __shared__ int lds[];                   // nbins ints + nbins floats
    int* hc = lds;
    float* hw = (float*)(lds + nbins);
    for (int i = threadIdx.x; i < nbins; i += blockDim.x) { hc[i] = 0; hw[i] = 0.f; }
    __syncthreads();
    int b = blockIdx.x;
    int lo = b * chunk, hi = min(lo + chunk, E);
    for (int e = lo + threadIdx.x; e < hi; e += blockDim.x) {
        int d = dst[e];
        atomicAdd(&hc[d], 1);                      // LDS atomic
        atomicAdd(&hw[d], fabsf(ea[e]));           // LDS atomic
    }
    __syncthreads();
    for (int i = threadIdx.x; i < nbins; i += blockDim.x) {
        part[b * nbins + i]  = hc[i];
        partw[b * nbins + i] = hw[i];
    }
}

// one 1024-thread block: offsets = exscan(bin totals); part[b][i] overwritten in
// place with global start cursor for (block b, bin i); wsum finalized; pool zeroed.
__global__ void k_scan(int* __restrict__ part, const float* __restrict__ partw,
                       int* __restrict__ offsets, float* __restrict__ wsum,
                       float* __restrict__ pool, int nbins, int nb, int poolN) {
    __shared__ int wtot[16];
    int t = threadIdx.x;
    int chunk = (nbins + 1023) / 1024;
    int lo = t * chunk, hi = min(lo + chunk, nbins);
    int s = 0;
    for (int i = lo; i < hi; i++) {
        int tot = 0;
        for (int b = 0; b < nb; b++) tot += part[b * nbins + i];
        s += tot;
    }
    int lane = t & 63, wid = t >> 6;
    int v = s;
    for (int d = 1; d < 64; d <<= 1) { int u = __shfl_up(v, d); if (lane >= d) v += u; }
    if (lane == 63) wtot[wid] = v;
    __syncthreads();
    if (wid == 0) {
        int w = (lane < 16) ? wtot[lane] : 0;
        for (int d = 1; d < 16; d <<= 1) { int u = __shfl_up(w, d); if (lane >= d) w += u; }
        if (lane < 16) wtot[lane] = w;
    }
    __syncthreads();
    int run = (wid > 0 ? wtot[wid - 1] : 0) + (v - s);   // exclusive prefix
    for (int i = lo; i < hi; i++) {
        offsets[i] = run;
        int c = run;
        float w = 0.f;
        for (int b = 0; b < nb; b++) {
            int p = part[b * nbins + i];
            part[b * nbins + i] = c;               // reuse as start cursor
            c += p;
            w += partw[b * nbins + i];
        }
        wsum[i] = w;
        run = c;
    }
    if (lo < nbins && hi == nbins) offsets[nbins] = run;
    if (t < poolN) pool[t] = 0.f;
}

// scatter with LDS cursors (no global atomics); 2B payload.
__global__ void k_scatter(const int* __restrict__ src, const int* __restrict__ dst,
                          const int* __restrict__ start, ushort_t* __restrict__ ssrc,
                          int E, int nbins, int chunk) {
    extern __shared__ int cur[];                   // nbins ints
    int b = blockIdx.x;
    for (int i = threadIdx.x; i < nbins; i += blockDim.x) cur[i] = start[b * nbins + i];
    __syncthreads();
    int lo = b * chunk, hi = min(lo + chunk, E);
    for (int e = lo + threadIdx.x; e < hi; e += blockDim.x) {
        int d = dst[e];
        int p = atomicAdd(&cur[d], 1);             // LDS atomic
        ssrc[p] = (ushort_t)src[e];
    }
}

// shared epilogue: given xp (lane l of a 32-lane group holds xp[row][l]), compute
// als/ald (group reduce) and ys/yd (group broadcast matmul vs elw).
__device__ __forceinline__ void node_epilogue(float xp, int r, int l,
        const float* __restrict__ asrc, const float* __restrict__ adst,
        const float* __restrict__ elw,
        float* __restrict__ ys, float* __restrict__ yd,
        float* __restrict__ als, float* __restrict__ ald) {
    float ps = xp * asrc[l], pd = xp * adst[l];
    #pragma unroll
    for (int mask = 16; mask >= 1; mask >>= 1) {
        ps += __shfl_xor(ps, mask);
        pd += __shfl_xor(pd, mask);
    }
    if (l == 0) { als[r] = ps; ald[r] = pd; }
    int gbase = threadIdx.x & 32;   // group base lane within the 64-wide wave
    float yss = 0.f, ydd = 0.f;
    #pragma unroll
    for (int k = 0; k < HID; k++) {
        float xk = __shfl(xp, gbase + k);
        yss = fmaf(xk, elw[(HID + k) * HID + l], yss);
        ydd = fmaf(xk, elw[k * HID + l], ydd);
    }
    ys[r * HID + l] = yss;
    yd[r * HID + l] = ydd;
}

// block 1 prep: xp = x @ w1 (K=200, w1 staged in LDS), fused epilogue.
__global__ void k_b1prep(const float* __restrict__ x, const float* __restrict__ w1,
                         const float* __restrict__ asrc, const float* __restrict__ adst,
                         const float* __restrict__ elw,
                         float* __restrict__ ys, float* __restrict__ yd,
                         float* __restrict__ als, float* __restrict__ ald,
                         int n, int K) {
    extern __shared__ float wlds[];                 // K*32 floats
    for (int i = threadIdx.x; i < K * HID; i += blockDim.x) wlds[i] = w1[i];
    __syncthreads();
    int l = threadIdx.x & 31;
    int r = blockIdx.x * (blockDim.x >> 5) + (threadIdx.x >> 5);
    if (r >= n) return;
    const float4* rowv = (const float4*)(x + (size_t)r * K);
    float acc = 0.f;
    for (int k4 = 0; k4 < (K >> 2); k4++) {
        float4 v = rowv[k4];                        // broadcast within group
        int k = k4 << 2;
        acc = fmaf(v.x, wlds[(k + 0) * HID + l], acc);
        acc = fmaf(v.y, wlds[(k + 1) * HID + l], acc);
        acc = fmaf(v.z, wlds[(k + 2) * HID + l], acc);
        acc = fmaf(v.w, wlds[(k + 3) * HID + l], acc);
    }
    node_epilogue(acc, r, l, asrc, adst, elw, ys, yd, als, ald);
}

// block 2 prep: xp = zb @ w2 (32x32 via shfl broadcast), fused epilogue.
__global__ void k_b2prep(const float* __restrict__ zb, const float* __restrict__ w2,
                         const float* __restrict__ asrc, const float* __restrict__ adst,
                         const float* __restrict__ elw,
                         float* __restrict__ ys, float* __restrict__ yd,
                         float* __restrict__ als, float* __restrict__ ald, int n) {
    int l = threadIdx.x & 31;
    int r = blockIdx.x * (blockDim.x >> 5) + (threadIdx.x >> 5);
    if (r >= n) return;
    float zv = zb[r * HID + l];
    int gbase = threadIdx.x & 32;
    float acc = 0.f;
    #pragma unroll
    for (int k = 0; k < HID; k++) {
        float zk = __shfl(zv, gbase + k);
        acc = fmaf(zk, w2[k * HID + l], acc);
    }
    node_epilogue(acc, r, l, asrc, adst, elw, ys, yd, als, ald);
}

// One wave per node: online-softmax weighted accumulate + fused proj+BN (+pool).
template<bool POOL>
__global__ void k_gat(const int* __restrict__ offsets, const ushort_t* __restrict__ ssrc,
                      const float* __restrict__ wsum, const float* __restrict__ als,
                      const float* __restrict__ ald, const float* __restrict__ ys,
                      const float* __restrict__ yd, const float* __restrict__ elw,
                      const float* __restrict__ elb, const float* __restrict__ bvec,
                      const float* __restrict__ pw, const float* __restrict__ pb,
                      const float* __restrict__ bng, const float* __restrict__ bnb,
                      float* __restrict__ zout, float* __restrict__ pool,
                      const int* __restrict__ batch, int n) {
    int lane = threadIdx.x & 63;
    int node = blockIdx.x * (blockDim.x >> 6) + (threadIdx.x >> 6);
    if (node >= n) return;
    int beg = offsets[node], end = offsets[node + 1];
    int deg = end - beg;
    int half = lane >> 5, l = lane & 31;
    float aldi = ald[node];
    float agg;
    if (deg > 0) {
        int mid = beg + (deg >> 1);
        int e  = half ? mid : beg;
        int e1 = half ? end : mid;
        float m = -INFINITY, acc = 0.f, esum = 0.f;
        for (; e + 8 <= e1; e += 8) {
            int j0 = ssrc[e + 0], j1 = ssrc[e + 1], j2 = ssrc[e + 2], j3 = ssrc[e + 3];
            int j4 = ssrc[e + 4], j5 = ssrc[e + 5], j6 = ssrc[e + 6], j7 = ssrc[e + 7];
            float a0 = als[j0] + aldi, a1 = als[j1] + aldi, a2 = als[j2] + aldi, a3 = als[j3] + aldi;
            float a4 = als[j4] + aldi, a5 = als[j5] + aldi, a6 = als[j6] + aldi, a7 = als[j7] + aldi;
            a0 = (a0 >= 0.f) ? a0 : 0.2f * a0;  a1 = (a1 >= 0.f) ? a1 : 0.2f * a1;
            a2 = (a2 >= 0.f) ? a2 : 0.2f * a2;  a3 = (a3 >= 0.f) ? a3 : 0.2f * a3;
            a4 = (a4 >= 0.f) ? a4 : 0.2f * a4;  a5 = (a5 >= 0.f) ? a5 : 0.2f * a5;
            a6 = (a6 >= 0.f) ? a6 : 0.2f * a6;  a7 = (a7 >= 0.f) ? a7 : 0.2f * a7;
            float cmax = fmaxf(fmaxf(fmaxf(a0, a1), fmaxf(a2, a3)),
                               fmaxf(fmaxf(a4, a5), fmaxf(a6, a7)));
            if (cmax > m) { float sc = __expf(m - cmax); acc *= sc; esum *= sc; m = cmax; }
            float w0 = __expf(a0 - m), w1 = __expf(a1 - m), w2 = __expf(a2 - m), w3 = __expf(a3 - m);
            float w4 = __expf(a4 - m), w5 = __expf(a5 - m), w6 = __expf(a6 - m), w7 = __expf(a7 - m);
            acc = fmaf(w0, ys[j0 * HID + l], acc);  esum += w0;
            acc = fmaf(w1, ys[j1 * HID + l], acc);  esum += w1;
            acc = fmaf(w2, ys[j2 * HID + l], acc);  esum += w2;
            acc = fmaf(w3, ys[j3 * HID + l], acc);  esum += w3;
            acc = fmaf(w4, ys[j4 * HID + l], acc);  esum += w4;
            acc = fmaf(w5, ys[j5 * HID + l], acc);  esum += w5;
            acc = fmaf(w6, ys[j6 * HID + l], acc);  esum += w6;
            acc = fmaf(w7, ys[j7 * HID + l], acc);  esum += w7;
        }
        for (; e < e1; e++) {
            int j = ssrc[e];
            float a = als[j] + aldi;
            a = (a >= 0.f) ? a : 0.2f * a;
            if (a > m) { float sc = __expf(m - a); acc *= sc; esum *= sc; m = a; }
            float w = __expf(a - m);
            acc = fmaf(w, ys[j * HID + l], acc);
            esum += w;
        }
        // merge the two half-waves (empty half: m=-inf -> weight exp(-inf)=0)
        float mo = __shfl_xor(m, 32);
        float M  = fmaxf(m, mo);
        float c0 = __expf(m - M), c1 = __expf(mo - M);
        float se = esum * c0 + __shfl_xor(esum, 32) * c1;
        acc      = acc  * c0 + __shfl_xor(acc, 32)  * c1;
        agg = acc / se + wsum[node] * elw[64 * HID + l];
    } else {
        agg = 0.f;
    }
    agg += (float)deg * (yd[node * HID + l] + elb[l]) + bvec[l];
    // projection 32x32 via shfl broadcast, then LeakyReLU + BatchNorm(eval)
    float z = 0.f;
    #pragma unroll
    for (int k = 0; k < HID; k++) {
        float av = __shfl(agg, k);                  // agg identical on both halves
        z = fmaf(av, pw[k * HID + l], z);
    }
    z += pb[l];
    z = (z >= 0.f) ? z : 0.2f * z;
    const float inv = 0.99999500003749971875f;      // 1/sqrt(1+1e-5)
    z = fmaf(z, bng[l] * inv, bnb[l]);
    if (lane < 32) {
        if (POOL) atomicAdd(&pool[batch[node] * HID + l], z);
        else      zout[node * HID + l] = z;
    }
}

__global__ void k_head(const float* __restrict__ pool, const int* __restrict__ batch,
                       const float* __restrict__ fw, const float* __restrict__ fb,
                       float* __restrict__ out, int n, int ngraphs, int ncls) {
    __shared__ int scnt[64];
    int t = threadIdx.x;
    if (t < ngraphs) scnt[t] = 0;
    __syncthreads();
    for (int i = t; i < n; i += blockDim.x) atomicAdd(&scnt[batch[i]], 1);
    __syncthreads();
    if (t < ngraphs * ncls) {
        int g = t / ncls, c = t % ncls;
        float cc = fmaxf((float)scnt[g], 1.0f);
        float acc = 0.f;
        for (int k = 0; k < HID; k++)
            acc = fmaf(pool[g * HID + k] / cc, fw[k * ncls + c], acc);
        out[t] = acc + fb[c];
    }
}

extern "C" void kernel_launch(void* const* d_in, const int* in_sizes, int n_in,
                              void* d_out, int out_size, void* d_ws, size_t ws_size,
                              hipStream_t stream) {
    const float* x     = (const float*)d_in[0];
    const float* ea    = (const float*)d_in[1];
    const int*   eidx  = (const int*)d_in[2];
    const int*   batch = (const int*)d_in[3];
    const float* w1    = (const float*)d_in[4];
    const float* asrc1 = (const float*)d_in[5];
    const float* adst1 = (const float*)d_in[6];
    const float* b1    = (const float*)d_in[7];
    const float* elw1  = (const float*)d_in[8];
    const float* elb1  = (const float*)d_in[9];
    const float* pw1   = (const float*)d_in[10];
    const float* pb1   = (const float*)d_in[11];
    const float* bng1  = (const float*)d_in[12];
    const float* bnb1  = (const float*)d_in[13];
    const float* w2    = (const float*)d_in[14];
    const float* asrc2 = (const float*)d_in[15];
    const float* adst2 = (const float*)d_in[16];
    const float* b2    = (const float*)d_in[17];
    const float* elw2  = (const float*)d_in[18];
    const float* elb2  = (const float*)d_in[19];
    const float* pw2   = (const float*)d_in[20];
    const float* pb2   = (const float*)d_in[21];
    const float* bng2  = (const float*)d_in[22];
    const float* bnb2  = (const float*)d_in[23];
    const float* fw    = (const float*)d_in[24];
    const float* fb    = (const float*)d_in[25];

    const int E  = in_sizes[1];
    const int N  = in_sizes[3];
    const int K1 = in_sizes[4] / HID;        // 200
    const int NCLS = in_sizes[25];           // 2
    const int NG = out_size / NCLS;          // 32

    float* ws = (float*)d_ws;
    size_t off = 0;
    auto alloc = [&](size_t nelem) { size_t r = off; off += nelem; return r; };
    int*      part    = (int*)(ws + alloc((size_t)NB_SORT * N));   // becomes start cursors
    float*    partw   = ws + alloc((size_t)NB_SORT * N);
    int*      offsets = (int*)(ws + alloc(N + 1));
    float*    wsum    = ws + alloc(N);
    ushort_t* ssrc    = (ushort_t*)(ws + alloc((E + 1) / 2));
    float*    ys      = ws + alloc((size_t)N * HID);
    float*    yd      = ws + alloc((size_t)N * HID);
    float*    zb      = ws + alloc((size_t)N * HID);
    float*    als     = ws + alloc(N);
    float*    ald     = ws + alloc(N);
    float*    pool    = ws + alloc((size_t)NG * HID);
    (void)ws_size; (void)n_in;

    const int chunk = (E + NB_SORT - 1) / NB_SORT;

    // ---- atomic-free counting sort of edges by dst (shared by both blocks) ----
    k_part_hist<<<NB_SORT, 256, 2 * N * sizeof(int), stream>>>(
        eidx + E, ea, part, partw, E, N, chunk);
    k_scan<<<1, 1024, 0, stream>>>(part, partw, offsets, wsum, pool, N, NB_SORT, NG * HID);
    k_scatter<<<NB_SORT, 256, N * sizeof(int), stream>>>(
        eidx, eidx + E, part, ssrc, E, N, chunk);

    int gb8 = (N + 7) / 8;

    // ---- block 1 ----
    k_b1prep<<<gb8, 256, K1 * HID * sizeof(float), stream>>>(
        x, w1, asrc1, adst1, elw1, ys, yd, als, ald, N, K1);
    k_gat<false><<<(N + 3) / 4, 256, 0, stream>>>(offsets, ssrc, wsum, als, ald, ys, yd,
        elw1, elb1, b1, pw1, pb1, bng1, bnb1, zb, nullptr, batch, N);

    // ---- block 2 (pool fused into gat epilogue) ----
    k_b2prep<<<gb8, 256, 0, stream>>>(zb, w2, asrc2, adst2, elw2, ys, yd, als, ald, N);
    k_gat<true><<<(N + 3) / 4, 256, 0, stream>>>(offsets, ssrc, wsum, als, ald, ys, yd,
        elw2, elb2, b2, pw2, pb2, bng2, bnb2, nullptr, pool, batch, N);

    // ---- head (computes per-graph counts itself) ----
    k_head<<<1, 256, 0, stream>>>(pool, batch, fw, fb, (float*)d_out, N, NG, NCLS);
}

// Round 5
// 207.636 us; speedup vs baseline: 4.6153x; 4.6153x over previous
//
#include <hip/hip_runtime.h>
#include <hip/hip_bf16.h>

// GAT_51788715655952. Atomic-free counting sort of edges by dst (2B src payload);
// per-node wave does online-softmax weighted sum of ys[src]; edge-linear decomposed:
//   agg[i] = deg*(yd[i]+elb) + (sum_e w_e*ys[src_e])/sum_e w_e + wsum[i]*elw[64] + b
// Sort pipeline: LDS histograms -> parallel column-reduce -> tiny scan -> parallel
// column-prefix (cursors) -> LDS-cursor scatter. No device-scope atomics in the
// sort (round-3: 2.56M atomics = 77MB HBM writes; round-4: serial strided scan
// in one block = 815us. Both fixed by bin-parallel coalesced column walks).

#define HID 32
#define NB_SORT 128

typedef unsigned short ushort_t;

// per-block LDS histogram: counts + sum|ea| per dst bin, written as partials.
__global__ void k_part_hist(const int* __restrict__ dst, const float* __restrict__ ea,
                            int* __restrict__ part, float* __restrict__ partw,
                            int E, int nbins, int chunk) {
    extern __shared__ int lds[];                   // nbins ints + nbins floats
    int* hc = lds;
    float* hw = (float*)(lds + nbins);
    for (int i = threadIdx.x; i < nbins; i += blockDim.x) { hc[i] = 0; hw[i] = 0.f; }
    __syncthreads();
    int b = blockIdx.x;
    int lo = b * chunk, hi = min(lo + chunk, E);
    for (int e = lo + threadIdx.x; e < hi; e += blockDim.x) {
        int d = dst[e];
        atomicAdd(&hc[d], 1);                      // LDS atomic
        atomicAdd(&hw[d], fabsf(ea[e]));           // LDS atomic
    }
    __syncthreads();
    for (int i = threadIdx.x; i < nbins; i += blockDim.x) {
        part[b * nbins + i]  = hc[i];
        partw[b * nbins + i] = hw[i];
    }
}

// bin-parallel column reduce: totals[i] = sum_b part[b][i]; wsum[i] = sum_b partw[b][i].
// consecutive threads own consecutive bins -> every load is wave-coalesced.
__global__ void k_reduce(const int* __restrict__ part, const float* __restrict__ partw,
                         int* __restrict__ totals, float* __restrict__ wsum,
                         int nbins, int nb) {
    int i = blockIdx.x * blockDim.x + threadIdx.x;
    if (i >= nbins) return;
    int t = 0; float w = 0.f;
    for (int b = 0; b < nb; b++) {
        t += part[b * nbins + i];
        w += partw[b * nbins + i];
    }
    totals[i] = t;
    wsum[i] = w;
}

// single block: exclusive scan of totals[nbins] -> offsets[nbins+1]; zero pool.
__global__ void k_scan_small(const int* __restrict__ totals, int* __restrict__ offsets,
                             float* __restrict__ pool, int nbins, int poolN) {
    __shared__ int wtot[16];
    int t = threadIdx.x;
    int chunk = (nbins + 1023) / 1024;
    int lo = t * chunk, hi = min(lo + chunk, nbins);
    int s = 0;
    for (int i = lo; i < hi; i++) s += totals[i];
    int lane = t & 63, wid = t >> 6;
    int v = s;
    for (int d = 1; d < 64; d <<= 1) { int u = __shfl_up(v, d); if (lane >= d) v += u; }
    if (lane == 63) wtot[wid] = v;
    __syncthreads();
    if (wid == 0) {
        int w = (lane < 16) ? wtot[lane] : 0;
        for (int d = 1; d < 16; d <<= 1) { int u = __shfl_up(w, d); if (lane >= d) w += u; }
        if (lane < 16) wtot[lane] = w;
    }
    __syncthreads();
    int run = (wid > 0 ? wtot[wid - 1] : 0) + (v - s);   // exclusive prefix
    for (int i = lo; i < hi; i++) {
        offsets[i] = run;
        run += totals[i];
    }
    if (lo < nbins && hi == nbins) offsets[nbins] = run;
    if (t < poolN) pool[t] = 0.f;
}

// bin-parallel column prefix: part[b][i] <- offsets[i] + sum_{b'<b} part[b'][i].
__global__ void k_colscan(int* __restrict__ part, const int* __restrict__ offsets,
                          int nbins, int nb) {
    int i = blockIdx.x * blockDim.x + threadIdx.x;
    if (i >= nbins) return;
    int c = offsets[i];
    for (int b = 0; b < nb; b++) {
        int p = part[b * nbins + i];
        part[b * nbins + i] = c;
        c += p;
    }
}

// scatter with LDS cursors (no global atomics); 2B payload.
__global__ void k_scatter(const int* __restrict__ src, const int* __restrict__ dst,
                          const int* __restrict__ start, ushort_t* __restrict__ ssrc,
                          int E, int nbins, int chunk) {
    extern __shared__ int cur[];                   // nbins ints
    int b = blockIdx.x;
    for (int i = threadIdx.x; i < nbins; i += blockDim.x) cur[i] = start[b * nbins + i];
    __syncthreads();
    int lo = b * chunk, hi = min(lo + chunk, E);
    for (int e = lo + threadIdx.x; e < hi; e += blockDim.x) {
        int d = dst[e];
        int p = atomicAdd(&cur[d], 1);             // LDS atomic
        ssrc[p] = (ushort_t)src[e];
    }
}

// shared epilogue: given xp (lane l of a 32-lane group holds xp[row][l]), compute
// als/ald (group reduce) and ys/yd (group broadcast matmul vs elw).
__device__ __forceinline__ void node_epilogue(float xp, int r, int l,
        const float* __restrict__ asrc, const float* __restrict__ adst,
        const float* __restrict__ elw,
        float* __restrict__ ys, float* __restrict__ yd,
        float* __restrict__ als, float* __restrict__ ald) {
    float ps = xp * asrc[l], pd = xp * adst[l];
    #pragma unroll
    for (int mask = 16; mask >= 1; mask >>= 1) {
        ps += __shfl_xor(ps, mask);
        pd += __shfl_xor(pd, mask);
    }
    if (l == 0) { als[r] = ps; ald[r] = pd; }
    int gbase = threadIdx.x & 32;   // group base lane within the 64-wide wave
    float yss = 0.f, ydd = 0.f;
    #pragma unroll
    for (int k = 0; k < HID; k++) {
        float xk = __shfl(xp, gbase + k);
        yss = fmaf(xk, elw[(HID + k) * HID + l], yss);
        ydd = fmaf(xk, elw[k * HID + l], ydd);
    }
    ys[r * HID + l] = yss;
    yd[r * HID + l] = ydd;
}

// block 1 prep: xp = x @ w1 (K=200, w1 staged in LDS), fused epilogue.
__global__ void k_b1prep(const float* __restrict__ x, const float* __restrict__ w1,
                         const float* __restrict__ asrc, const float* __restrict__ adst,
                         const float* __restrict__ elw,
                         float* __restrict__ ys, float* __restrict__ yd,
                         float* __restrict__ als, float* __restrict__ ald,
                         int n, int K) {
    extern __shared__ float wlds[];                 // K*32 floats
    for (int i = threadIdx.x; i < K * HID; i += blockDim.x) wlds[i] = w1[i];
    __syncthreads();
    int l = threadIdx.x & 31;
    int r = blockIdx.x * (blockDim.x >> 5) + (threadIdx.x >> 5);
    if (r >= n) return;
    const float4* rowv = (const float4*)(x + (size_t)r * K);
    float acc = 0.f;
    for (int k4 = 0; k4 < (K >> 2); k4++) {
        float4 v = rowv[k4];                        // broadcast within group
        int k = k4 << 2;
        acc = fmaf(v.x, wlds[(k + 0) * HID + l], acc);
        acc = fmaf(v.y, wlds[(k + 1) * HID + l], acc);
        acc = fmaf(v.z, wlds[(k + 2) * HID + l], acc);
        acc = fmaf(v.w, wlds[(k + 3) * HID + l], acc);
    }
    node_epilogue(acc, r, l, asrc, adst, elw, ys, yd, als, ald);
}

// block 2 prep: xp = zb @ w2 (32x32 via shfl broadcast), fused epilogue.
__global__ void k_b2prep(const float* __restrict__ zb, const float* __restrict__ w2,
                         const float* __restrict__ asrc, const float* __restrict__ adst,
                         const float* __restrict__ elw,
                         float* __restrict__ ys, float* __restrict__ yd,
                         float* __restrict__ als, float* __restrict__ ald, int n) {
    int l = threadIdx.x & 31;
    int r = blockIdx.x * (blockDim.x >> 5) + (threadIdx.x >> 5);
    if (r >= n) return;
    float zv = zb[r * HID + l];
    int gbase = threadIdx.x & 32;
    float acc = 0.f;
    #pragma unroll
    for (int k = 0; k < HID; k++) {
        float zk = __shfl(zv, gbase + k);
        acc = fmaf(zk, w2[k * HID + l], acc);
    }
    node_epilogue(acc, r, l, asrc, adst, elw, ys, yd, als, ald);
}

// One wave per node: online-softmax weighted accumulate + fused proj+BN (+pool).
template<bool POOL>
__global__ void k_gat(const int* __restrict__ offsets, const ushort_t* __restrict__ ssrc,
                      const float* __restrict__ wsum, const float* __restrict__ als,
                      const float* __restrict__ ald, const float* __restrict__ ys,
                      const float* __restrict__ yd, const float* __restrict__ elw,
                      const float* __restrict__ elb, const float* __restrict__ bvec,
                      const float* __restrict__ pw, const float* __restrict__ pb,
                      const float* __restrict__ bng, const float* __restrict__ bnb,
                      float* __restrict__ zout, float* __restrict__ pool,
                      const int* __restrict__ batch, int n) {
    int lane = threadIdx.x & 63;
    int node = blockIdx.x * (blockDim.x >> 6) + (threadIdx.x >> 6);
    if (node >= n) return;
    int beg = offsets[node], end = offsets[node + 1];
    int deg = end - beg;
    int half = lane >> 5, l = lane & 31;
    float aldi = ald[node];
    float agg;
    if (deg > 0) {
        int mid = beg + (deg >> 1);
        int e  = half ? mid : beg;
        int e1 = half ? end : mid;
        float m = -INFINITY, acc = 0.f, esum = 0.f;
        for (; e + 8 <= e1; e += 8) {
            int j0 = ssrc[e + 0], j1 = ssrc[e + 1], j2 = ssrc[e + 2], j3 = ssrc[e + 3];
            int j4 = ssrc[e + 4], j5 = ssrc[e + 5], j6 = ssrc[e + 6], j7 = ssrc[e + 7];
            float a0 = als[j0] + aldi, a1 = als[j1] + aldi, a2 = als[j2] + aldi, a3 = als[j3] + aldi;
            float a4 = als[j4] + aldi, a5 = als[j5] + aldi, a6 = als[j6] + aldi, a7 = als[j7] + aldi;
            a0 = (a0 >= 0.f) ? a0 : 0.2f * a0;  a1 = (a1 >= 0.f) ? a1 : 0.2f * a1;
            a2 = (a2 >= 0.f) ? a2 : 0.2f * a2;  a3 = (a3 >= 0.f) ? a3 : 0.2f * a3;
            a4 = (a4 >= 0.f) ? a4 : 0.2f * a4;  a5 = (a5 >= 0.f) ? a5 : 0.2f * a5;
            a6 = (a6 >= 0.f) ? a6 : 0.2f * a6;  a7 = (a7 >= 0.f) ? a7 : 0.2f * a7;
            float cmax = fmaxf(fmaxf(fmaxf(a0, a1), fmaxf(a2, a3)),
                               fmaxf(fmaxf(a4, a5), fmaxf(a6, a7)));
            if (cmax > m) { float sc = __expf(m - cmax); acc *= sc; esum *= sc; m = cmax; }
            float w0 = __expf(a0 - m), w1 = __expf(a1 - m), w2 = __expf(a2 - m), w3 = __expf(a3 - m);
            float w4 = __expf(a4 - m), w5 = __expf(a5 - m), w6 = __expf(a6 - m), w7 = __expf(a7 - m);
            acc = fmaf(w0, ys[j0 * HID + l], acc);  esum += w0;
            acc = fmaf(w1, ys[j1 * HID + l], acc);  esum += w1;
            acc = fmaf(w2, ys[j2 * HID + l], acc);  esum += w2;
            acc = fmaf(w3, ys[j3 * HID + l], acc);  esum += w3;
            acc = fmaf(w4, ys[j4 * HID + l], acc);  esum += w4;
            acc = fmaf(w5, ys[j5 * HID + l], acc);  esum += w5;
            acc = fmaf(w6, ys[j6 * HID + l], acc);  esum += w6;
            acc = fmaf(w7, ys[j7 * HID + l], acc);  esum += w7;
        }
        for (; e < e1; e++) {
            int j = ssrc[e];
            float a = als[j] + aldi;
            a = (a >= 0.f) ? a : 0.2f * a;
            if (a > m) { float sc = __expf(m - a); acc *= sc; esum *= sc; m = a; }
            float w = __expf(a - m);
            acc = fmaf(w, ys[j * HID + l], acc);
            esum += w;
        }
        // merge the two half-waves (empty half: m=-inf -> weight exp(-inf)=0)
        float mo = __shfl_xor(m, 32);
        float M  = fmaxf(m, mo);
        float c0 = __expf(m - M), c1 = __expf(mo - M);
        float se = esum * c0 + __shfl_xor(esum, 32) * c1;
        acc      = acc  * c0 + __shfl_xor(acc, 32)  * c1;
        agg = acc / se + wsum[node] * elw[64 * HID + l];
    } else {
        agg = 0.f;
    }
    agg += (float)deg * (yd[node * HID + l] + elb[l]) + bvec[l];
    // projection 32x32 via shfl broadcast, then LeakyReLU + BatchNorm(eval)
    float z = 0.f;
    #pragma unroll
    for (int k = 0; k < HID; k++) {
        float av = __shfl(agg, k);                  // agg identical on both halves
        z = fmaf(av, pw[k * HID + l], z);
    }
    z += pb[l];
    z = (z >= 0.f) ? z : 0.2f * z;
    const float inv = 0.99999500003749971875f;      // 1/sqrt(1+1e-5)
    z = fmaf(z, bng[l] * inv, bnb[l]);
    if (lane < 32) {
        if (POOL) atomicAdd(&pool[batch[node] * HID + l], z);
        else      zout[node * HID + l] = z;
    }
}

__global__ void k_head(const float* __restrict__ pool, const int* __restrict__ batch,
                       const float* __restrict__ fw, const float* __restrict__ fb,
                       float* __restrict__ out, int n, int ngraphs, int ncls) {
    __shared__ int scnt[64];
    int t = threadIdx.x;
    if (t < ngraphs) scnt[t] = 0;
    __syncthreads();
    for (int i = t; i < n; i += blockDim.x) atomicAdd(&scnt[batch[i]], 1);
    __syncthreads();
    if (t < ngraphs * ncls) {
        int g = t / ncls, c = t % ncls;
        float cc = fmaxf((float)scnt[g], 1.0f);
        float acc = 0.f;
        for (int k = 0; k < HID; k++)
            acc = fmaf(pool[g * HID + k] / cc, fw[k * ncls + c], acc);
        out[t] = acc + fb[c];
    }
}

extern "C" void kernel_launch(void* const* d_in, const int* in_sizes, int n_in,
                              void* d_out, int out_size, void* d_ws, size_t ws_size,
                              hipStream_t stream) {
    const float* x     = (const float*)d_in[0];
    const float* ea    = (const float*)d_in[1];
    const int*   eidx  = (const int*)d_in[2];
    const int*   batch = (const int*)d_in[3];
    const float* w1    = (const float*)d_in[4];
    const float* asrc1 = (const float*)d_in[5];
    const float* adst1 = (const float*)d_in[6];
    const float* b1    = (const float*)d_in[7];
    const float* elw1  = (const float*)d_in[8];
    const float* elb1  = (const float*)d_in[9];
    const float* pw1   = (const float*)d_in[10];
    const float* pb1   = (const float*)d_in[11];
    const float* bng1  = (const float*)d_in[12];
    const float* bnb1  = (const float*)d_in[13];
    const float* w2    = (const float*)d_in[14];
    const float* asrc2 = (const float*)d_in[15];
    const float* adst2 = (const float*)d_in[16];
    const float* b2    = (const float*)d_in[17];
    const float* elw2  = (const float*)d_in[18];
    const float* elb2  = (const float*)d_in[19];
    const float* pw2   = (const float*)d_in[20];
    const float* pb2   = (const float*)d_in[21];
    const float* bng2  = (const float*)d_in[22];
    const float* bnb2  = (const float*)d_in[23];
    const float* fw    = (const float*)d_in[24];
    const float* fb    = (const float*)d_in[25];

    const int E  = in_sizes[1];
    const int N  = in_sizes[3];
    const int K1 = in_sizes[4] / HID;        // 200
    const int NCLS = in_sizes[25];           // 2
    const int NG = out_size / NCLS;          // 32

    float* ws = (float*)d_ws;
    size_t off = 0;
    auto alloc = [&](size_t nelem) { size_t r = off; off += nelem; return r; };
    int*      part    = (int*)(ws + alloc((size_t)NB_SORT * N));   // becomes start cursors
    float*    partw   = ws + alloc((size_t)NB_SORT * N);
    int*      totals  = (int*)(ws + alloc(N));
    int*      offsets = (int*)(ws + alloc(N + 1));
    float*    wsum    = ws + alloc(N);
    ushort_t* ssrc    = (ushort_t*)(ws + alloc((E + 1) / 2));
    float*    ys      = ws + alloc((size_t)N * HID);
    float*    yd      = ws + alloc((size_t)N * HID);
    float*    zb      = ws + alloc((size_t)N * HID);
    float*    als     = ws + alloc(N);
    float*    ald     = ws + alloc(N);
    float*    pool    = ws + alloc((size_t)NG * HID);
    (void)ws_size; (void)n_in;

    const int chunk = (E + NB_SORT - 1) / NB_SORT;
    const int binb = (N + 255) / 256;

    // ---- atomic-free counting sort of edges by dst (shared by both blocks) ----
    k_part_hist<<<NB_SORT, 256, 2 * N * sizeof(int), stream>>>(
        eidx + E, ea, part, partw, E, N, chunk);
    k_reduce<<<binb, 256, 0, stream>>>(part, partw, totals, wsum, N, NB_SORT);
    k_scan_small<<<1, 1024, 0, stream>>>(totals, offsets, pool, N, NG * HID);
    k_colscan<<<binb, 256, 0, stream>>>(part, offsets, N, NB_SORT);
    k_scatter<<<NB_SORT, 256, N * sizeof(int), stream>>>(
        eidx, eidx + E, part, ssrc, E, N, chunk);

    int gb8 = (N + 7) / 8;

    // ---- block 1 ----
    k_b1prep<<<gb8, 256, K1 * HID * sizeof(float), stream>>>(
        x, w1, asrc1, adst1, elw1, ys, yd, als, ald, N, K1);
    k_gat<false><<<(N + 3) / 4, 256, 0, stream>>>(offsets, ssrc, wsum, als, ald, ys, yd,
        elw1, elb1, b1, pw1, pb1, bng1, bnb1, zb, nullptr, batch, N);

    // ---- block 2 (pool fused into gat epilogue) ----
    k_b2prep<<<gb8, 256, 0, stream>>>(zb, w2, asrc2, adst2, elw2, ys, yd, als, ald, N);
    k_gat<true><<<(N + 3) / 4, 256, 0, stream>>>(offsets, ssrc, wsum, als, ald, ys, yd,
        elw2, elb2, b2, pw2, pb2, bng2, bnb2, nullptr, pool, batch, N);

    // ---- head (computes per-graph counts itself) ----
    k_head<<<1, 256, 0, stream>>>(pool, batch, fw, fb, (float*)d_out, N, NG, NCLS);
}